// Round 1
// baseline (170.058 us; speedup 1.0000x reference)
//
#include <hip/hip_runtime.h>
#include <hip/hip_bf16.h>
#include <math.h>

// Problem constants (fixed by the reference)
constexpr int BROWS = 4096;   // batch
constexpr int DDIM  = 2048;   // input features (K)
constexpr int NCOMP = 4;
constexpr int DCOMP = 1024;
constexpr int NOUT  = NCOMP * DCOMP;  // 4096 output cols

typedef __attribute__((ext_vector_type(8))) short bf16x8;
typedef __attribute__((ext_vector_type(4))) float f32x4;
typedef __attribute__((ext_vector_type(4))) short s16x4;

__device__ __forceinline__ short f2bf(float f) {
  union { float f; unsigned u; } v; v.f = f;
  unsigned r = v.u + 0x7FFFu + ((v.u >> 16) & 1u);  // round-to-nearest-even
  return (short)(r >> 16);
}

// ---------------- Gating: H = x@Wg + bg + noise * softplus(x@Wn + bn) ----------------
// One wave per row; writes G (== monotonic mask, forward value) into Gout.
__global__ __launch_bounds__(256) void gating_kernel(
    const float* __restrict__ x, const float* __restrict__ noise,
    const float* __restrict__ Wg, const float* __restrict__ bg,
    const float* __restrict__ Wn, const float* __restrict__ bn,
    float* __restrict__ Gout) {
  const int lane = threadIdx.x & 63;
  const int row  = blockIdx.x * 4 + (threadIdx.x >> 6);
  const float* xr = x + (size_t)row * DDIM;

  float ag0=0.f, ag1=0.f, ag2=0.f, ag3=0.f;
  float an0=0.f, an1=0.f, an2=0.f, an3=0.f;
  for (int d = lane; d < DDIM; d += 64) {
    float xv = xr[d];
    float4 wg = *reinterpret_cast<const float4*>(Wg + 4*d);   // Wg[d][0..3]
    float4 wn = *reinterpret_cast<const float4*>(Wn + 4*d);
    ag0 += xv * wg.x; ag1 += xv * wg.y; ag2 += xv * wg.z; ag3 += xv * wg.w;
    an0 += xv * wn.x; an1 += xv * wn.y; an2 += xv * wn.z; an3 += xv * wn.w;
  }
#pragma unroll
  for (int off = 32; off > 0; off >>= 1) {
    ag0 += __shfl_xor(ag0, off); ag1 += __shfl_xor(ag1, off);
    ag2 += __shfl_xor(ag2, off); ag3 += __shfl_xor(ag3, off);
    an0 += __shfl_xor(an0, off); an1 += __shfl_xor(an1, off);
    an2 += __shfl_xor(an2, off); an3 += __shfl_xor(an3, off);
  }
  if (lane == 0) {
    float g[4]  = {ag0 + bg[0], ag1 + bg[1], ag2 + bg[2], ag3 + bg[3]};
    float nv[4] = {an0 + bn[0], an1 + bn[1], an2 + bn[2], an3 + bn[3]};
    float H[4];
#pragma unroll
    for (int i = 0; i < 4; i++) {
      float v  = nv[i];
      float sp = (v > 20.f) ? v : log1pf(expf(v));   // softplus, stable for our range
      H[i] = g[i] + noise[(size_t)row * NCOMP + i] * sp;
    }
    int k = 0; float best = H[0];
#pragma unroll
    for (int i = 1; i < 4; i++) { if (H[i] > best) { best = H[i]; k = i; } }
#pragma unroll
    for (int i = 0; i < 4; i++)
      Gout[(size_t)row * NCOMP + i] = (i <= k) ? 1.0f : 0.0f;
  }
}

// ---------------- Main GEMM: E = mask * (x @ Wc + bc) ----------------
// 128x128 tile, BK=32, 4 waves (2x2), mfma_f32_16x16x32_bf16.
// A LDS: [128 rows][stride 40 bf16]; B LDS transposed: [128 cols][stride 40 bf16].
constexpr int BM = 128, BN = 128, BK = 32;
constexpr int LDT = 40;   // padded LDS stride (bf16 elems): 80B rows -> 2-way-only conflicts

__global__ __launch_bounds__(256, 2) void gemm_kernel(
    const float* __restrict__ x, const float* __restrict__ Wc,
    const float* __restrict__ bc, const float* __restrict__ G,
    float* __restrict__ E) {
  __shared__ short Asm[BM * LDT];
  __shared__ short Bsm[BN * LDT];

  const int tid = threadIdx.x;
  const int tile_m = blockIdx.y, tile_n = blockIdx.x;
  const int row0  = tile_m * BM;
  const int gcol0 = tile_n * BN;
  const int comp  = gcol0 >> 10;           // 128-col tile lies within one component
  const int oc0   = gcol0 & (DCOMP - 1);
  const float* __restrict__ Wcn = Wc + (size_t)comp * DDIM * DCOMP + oc0;

  // B staging mapping: thread -> (column, k-halfblock)
  const int c_loc = tid & 127;
  const int kb    = (tid >> 7) * 16;

  const int wave = tid >> 6, lane = tid & 63;
  const int wr = (wave >> 1) * 64;   // wave's 64-row block
  const int wc = (wave & 1) * 64;    // wave's 64-col block
  const int fr = lane & 15;          // fragment row/col
  const int fq = lane >> 4;          // quad index

  f32x4 acc[4][4];
#pragma unroll
  for (int m = 0; m < 4; m++)
#pragma unroll
    for (int n = 0; n < 4; n++) acc[m][n] = f32x4{0.f, 0.f, 0.f, 0.f};

  for (int k0 = 0; k0 < DDIM; k0 += BK) {
    __syncthreads();   // previous tile's reads complete before overwrite
    // ---- stage A: 128x32 f32 -> bf16, row-major ----
#pragma unroll
    for (int i = 0; i < 4; i++) {
      int q  = tid + 256 * i;        // quad index over 128*32/4 = 1024 quads
      int r  = q >> 3;               // 0..127
      int k4 = (q & 7) * 4;          // 0..28
      float4 v = *reinterpret_cast<const float4*>(
          x + (size_t)(row0 + r) * DDIM + k0 + k4);
      s16x4 s; s.x = f2bf(v.x); s.y = f2bf(v.y); s.z = f2bf(v.z); s.w = f2bf(v.w);
      *reinterpret_cast<s16x4*>(&Asm[r * LDT + k4]) = s;
    }
    // ---- stage B: 32x128 f32, transposed into [col][k] ----
    {
      float bv[16];
#pragma unroll
      for (int j = 0; j < 16; j++)
        bv[j] = Wcn[(size_t)(k0 + kb + j) * DCOMP + c_loc];
      bf16x8 p0, p1;
#pragma unroll
      for (int j = 0; j < 8; j++) { p0[j] = f2bf(bv[j]); p1[j] = f2bf(bv[8 + j]); }
      *reinterpret_cast<bf16x8*>(&Bsm[c_loc * LDT + kb])     = p0;
      *reinterpret_cast<bf16x8*>(&Bsm[c_loc * LDT + kb + 8]) = p1;
    }
    __syncthreads();
    // ---- compute: 16 MFMAs, full BK=32 consumed per mfma ----
    bf16x8 afrag[4], bfrag[4];
#pragma unroll
    for (int m = 0; m < 4; m++)
      afrag[m] = *reinterpret_cast<const bf16x8*>(&Asm[(wr + m * 16 + fr) * LDT + fq * 8]);
#pragma unroll
    for (int n = 0; n < 4; n++)
      bfrag[n] = *reinterpret_cast<const bf16x8*>(&Bsm[(wc + n * 16 + fr) * LDT + fq * 8]);
#pragma unroll
    for (int m = 0; m < 4; m++)
#pragma unroll
      for (int n = 0; n < 4; n++)
        acc[m][n] = __builtin_amdgcn_mfma_f32_16x16x32_bf16(afrag[m], bfrag[n], acc[m][n], 0, 0, 0);
  }

  // ---- epilogue: + bias, * mask, store f32 ----
  const float* __restrict__ bcn = bc + comp * DCOMP + oc0;
#pragma unroll
  for (int m = 0; m < 4; m++) {
#pragma unroll
    for (int n = 0; n < 4; n++) {
      int col_l = wc + n * 16 + fr;
      float bias = bcn[col_l];
#pragma unroll
      for (int j = 0; j < 4; j++) {
        int grow = row0 + wr + m * 16 + fq * 4 + j;
        float mval = G[(size_t)grow * NCOMP + comp];
        E[(size_t)grow * NOUT + gcol0 + col_l] = mval * (acc[m][n][j] + bias);
      }
    }
  }
}

extern "C" void kernel_launch(void* const* d_in, const int* in_sizes, int n_in,
                              void* d_out, int out_size, void* d_ws, size_t ws_size,
                              hipStream_t stream) {
  const float* x     = (const float*)d_in[0];
  const float* noise = (const float*)d_in[1];
  const float* Wc    = (const float*)d_in[2];
  const float* bc    = (const float*)d_in[3];
  const float* Wg    = (const float*)d_in[4];
  const float* bg    = (const float*)d_in[5];
  const float* Wn    = (const float*)d_in[6];
  const float* bn    = (const float*)d_in[7];

  float* E = (float*)d_out;                                  // [4096, 4096]
  float* G = (float*)d_out + (size_t)BROWS * NOUT;           // [4096, 4]

  gating_kernel<<<BROWS / 4, 256, 0, stream>>>(x, noise, Wg, bg, Wn, bn, G);
  gemm_kernel<<<dim3(NOUT / BN, BROWS / BM), 256, 0, stream>>>(x, Wc, bc, G, E);
}

// Round 2
// 115.676 us; speedup vs baseline: 1.4701x; 1.4701x over previous
//
#include <hip/hip_runtime.h>
#include <hip/hip_bf16.h>
#include <math.h>

// Problem constants (fixed by the reference)
constexpr int BROWS = 4096;   // batch
constexpr int DDIM  = 2048;   // input features (K)
constexpr int NCOMP = 4;
constexpr int DCOMP = 1024;
constexpr int NOUT  = NCOMP * DCOMP;  // 4096 output cols

typedef __attribute__((ext_vector_type(8))) short bf16x8;
typedef __attribute__((ext_vector_type(4))) float f32x4;
typedef __attribute__((ext_vector_type(4))) short s16x4;

__device__ __forceinline__ short f2bf(float f) {
  union { float f; unsigned u; } v; v.f = f;
  unsigned r = v.u + 0x7FFFu + ((v.u >> 16) & 1u);  // round-to-nearest-even
  return (short)(r >> 16);
}

// global->LDS direct copy, 16B per lane. LDS dest is wave-uniform base + lane*16.
#define GLOAD_LDS16(gptr, lptr) __builtin_amdgcn_global_load_lds( \
    (const __attribute__((address_space(1))) void*)(gptr),        \
    (__attribute__((address_space(3))) void*)(lptr), 16, 0, 0)

// ---------------- Gating + x f32->bf16 conversion (fused: both read all of x) ----
// One wave per row. H = x@Wg + bg + noise*softplus(x@Wn + bn); G = monotonic mask.
__global__ __launch_bounds__(256) void gating_convert_kernel(
    const float* __restrict__ x, const float* __restrict__ noise,
    const float* __restrict__ Wg, const float* __restrict__ bg,
    const float* __restrict__ Wn, const float* __restrict__ bn,
    float* __restrict__ Gout, short* __restrict__ xb) {
  const int lane = threadIdx.x & 63;
  const int row  = blockIdx.x * 4 + (threadIdx.x >> 6);
  const float* xr = x + (size_t)row * DDIM;
  short* xbr = xb + (size_t)row * DDIM;

  float ag[4] = {0.f, 0.f, 0.f, 0.f};
  float an[4] = {0.f, 0.f, 0.f, 0.f};
#pragma unroll
  for (int i = 0; i < 8; i++) {
    int d = i * 256 + lane * 4;
    float4 v = *reinterpret_cast<const float4*>(xr + d);
    s16x4 s; s.x = f2bf(v.x); s.y = f2bf(v.y); s.z = f2bf(v.z); s.w = f2bf(v.w);
    *reinterpret_cast<s16x4*>(xbr + d) = s;
    float xv[4] = {v.x, v.y, v.z, v.w};
#pragma unroll
    for (int j = 0; j < 4; j++) {
      float4 wg = *reinterpret_cast<const float4*>(Wg + 4 * (d + j));
      float4 wn = *reinterpret_cast<const float4*>(Wn + 4 * (d + j));
      ag[0] += xv[j] * wg.x; ag[1] += xv[j] * wg.y;
      ag[2] += xv[j] * wg.z; ag[3] += xv[j] * wg.w;
      an[0] += xv[j] * wn.x; an[1] += xv[j] * wn.y;
      an[2] += xv[j] * wn.z; an[3] += xv[j] * wn.w;
    }
  }
#pragma unroll
  for (int off = 32; off > 0; off >>= 1) {
#pragma unroll
    for (int c = 0; c < 4; c++) {
      ag[c] += __shfl_xor(ag[c], off);
      an[c] += __shfl_xor(an[c], off);
    }
  }
  if (lane == 0) {
    float H[4];
#pragma unroll
    for (int c = 0; c < 4; c++) {
      float v  = an[c] + bn[c];
      float sp = (v > 20.f) ? v : log1pf(expf(v));   // stable softplus
      H[c] = (ag[c] + bg[c]) + noise[(size_t)row * NCOMP + c] * sp;
    }
    int k = 0; float best = H[0];
#pragma unroll
    for (int c = 1; c < 4; c++) { if (H[c] > best) { best = H[c]; k = c; } }
#pragma unroll
    for (int c = 0; c < 4; c++)
      Gout[(size_t)row * NCOMP + c] = (c <= k) ? 1.0f : 0.0f;
  }
}

// ---------------- Wc [n][d][o] f32 -> WcT [n*o][d] bf16 (B^T layout) -------------
// LDS-tiled 64x64 transpose; +1-pad f32 tile -> 2-way-only (free) bank aliasing.
__global__ __launch_bounds__(256) void transpose_kernel(
    const float* __restrict__ Wc, short* __restrict__ WcT) {
  __shared__ float tile[64][65];
  const int c  = blockIdx.z;
  const int d0 = blockIdx.y * 64, o0 = blockIdx.x * 64;
  const int col = threadIdx.x & 63, rb = threadIdx.x >> 6;

  const float* src = Wc + ((size_t)c * DDIM + d0) * DCOMP + o0;
#pragma unroll
  for (int i = 0; i < 16; i++) {
    int r = rb + i * 4;
    tile[r][col] = src[(size_t)r * DCOMP + col];
  }
  __syncthreads();
  short* dst = WcT + ((size_t)c * DCOMP + o0) * DDIM + d0;
#pragma unroll
  for (int i = 0; i < 16; i++) {
    int o = rb + i * 4;
    dst[(size_t)o * DDIM + col] = f2bf(tile[col][o]);
  }
}

// ---------------- Main GEMM: E = mask * (xb @ WcT^T + bc) ------------------------
// m97 structure: 128x128 tile, BK=32, 4 waves (2x2), global_load_lds width=16,
// linear LDS [128][32] bf16, 2-barrier K-loop, mfma_f32_16x16x32_bf16.
constexpr int BM = 128, BN = 128, BK = 32;

__global__ __launch_bounds__(256, 2) void gemm_kernel(
    const short* __restrict__ xb, const short* __restrict__ wt,
    const float* __restrict__ bc, const float* __restrict__ G,
    float* __restrict__ E) {
  __shared__ short Asm[BM * BK];   // 8 KB, row-major [128][32]
  __shared__ short Bsm[BN * BK];   // 8 KB, row-major [128][32] (cols of E)

  const int tid  = threadIdx.x;
  const int wave = tid >> 6, lane = tid & 63;
  const int row0  = blockIdx.y * BM;
  const int gcol0 = blockIdx.x * BN;
  const int comp  = gcol0 >> 10;

  // Staging map: flat short idx = wave*512 + lane*8  ->  r = wave*16+lane/4, k = (lane&3)*8
  const int sr = wave * 16 + (lane >> 2);
  const int sk = (lane & 3) * 8;
  const short* gA = xb + (size_t)(row0 + sr) * DDIM + sk;
  const short* gB = wt + (size_t)(gcol0 + sr) * DDIM + sk;
  short* lA = Asm + wave * 512;   // lane lands at +lane*8 shorts
  short* lB = Bsm + wave * 512;

  const int wr = (wave >> 1) * 64;  // wave's 64-row block
  const int wc = (wave & 1) * 64;   // wave's 64-col block
  const int fr = lane & 15;
  const int fq = lane >> 4;

  f32x4 acc[4][4];
#pragma unroll
  for (int m = 0; m < 4; m++)
#pragma unroll
    for (int n = 0; n < 4; n++) acc[m][n] = f32x4{0.f, 0.f, 0.f, 0.f};

  for (int k0 = 0; k0 < DDIM; k0 += BK) {
    __syncthreads();   // previous tile's ds_reads complete before overwrite
    GLOAD_LDS16(gA + k0,            lA);          // A rows 0..63
    GLOAD_LDS16(gA + 64 * DDIM + k0, lA + 2048);  // A rows 64..127
    GLOAD_LDS16(gB + k0,            lB);          // B rows 0..63
    GLOAD_LDS16(gB + 64 * DDIM + k0, lB + 2048);  // B rows 64..127
    __syncthreads();   // compiler drains vmcnt(0) before barrier -> LDS ready

    bf16x8 afrag[4], bfrag[4];
#pragma unroll
    for (int m = 0; m < 4; m++)
      afrag[m] = *reinterpret_cast<const bf16x8*>(&Asm[(wr + m * 16 + fr) * BK + fq * 8]);
#pragma unroll
    for (int n = 0; n < 4; n++)
      bfrag[n] = *reinterpret_cast<const bf16x8*>(&Bsm[(wc + n * 16 + fr) * BK + fq * 8]);
#pragma unroll
    for (int m = 0; m < 4; m++)
#pragma unroll
      for (int n = 0; n < 4; n++)
        acc[m][n] = __builtin_amdgcn_mfma_f32_16x16x32_bf16(afrag[m], bfrag[n], acc[m][n], 0, 0, 0);
  }

  // Epilogue: + bias, * mask, store f32. (C/D map: col=lane&15, row=(lane>>4)*4+reg)
  const float* __restrict__ bcn = bc + (gcol0 >> 10) * DCOMP + (gcol0 & (DCOMP - 1));
#pragma unroll
  for (int m = 0; m < 4; m++) {
#pragma unroll
    for (int n = 0; n < 4; n++) {
      int col_l = wc + n * 16 + fr;
      float bias = bcn[col_l];
#pragma unroll
      for (int j = 0; j < 4; j++) {
        int grow = row0 + wr + m * 16 + fq * 4 + j;
        float mval = G[(size_t)grow * NCOMP + comp];
        E[(size_t)grow * NOUT + gcol0 + col_l] = mval * (acc[m][n][j] + bias);
      }
    }
  }
}

extern "C" void kernel_launch(void* const* d_in, const int* in_sizes, int n_in,
                              void* d_out, int out_size, void* d_ws, size_t ws_size,
                              hipStream_t stream) {
  const float* x     = (const float*)d_in[0];
  const float* noise = (const float*)d_in[1];
  const float* Wc    = (const float*)d_in[2];
  const float* bc    = (const float*)d_in[3];
  const float* Wg    = (const float*)d_in[4];
  const float* bg    = (const float*)d_in[5];
  const float* Wn    = (const float*)d_in[6];
  const float* bn    = (const float*)d_in[7];

  float* E = (float*)d_out;                          // [4096, 4096]
  float* G = (float*)d_out + (size_t)BROWS * NOUT;   // [4096, 4]

  short* xb  = (short*)d_ws;                         // [4096][2048] bf16, 16 MB
  short* WcT = xb + (size_t)BROWS * DDIM;            // [4096][2048] bf16, 16 MB

  gating_convert_kernel<<<BROWS / 4, 256, 0, stream>>>(x, noise, Wg, bg, Wn, bn, G, xb);
  transpose_kernel<<<dim3(DCOMP / 64, DDIM / 64, NCOMP), 256, 0, stream>>>(Wc, WcT);
  gemm_kernel<<<dim3(NOUT / BN, BROWS / BM), 256, 0, stream>>>(xb, WcT, bc, G, E);
}

// Round 3
// 97.658 us; speedup vs baseline: 1.7414x; 1.1845x over previous
//
#include <hip/hip_runtime.h>
#include <hip/hip_bf16.h>
#include <math.h>

// Problem constants (fixed by the reference)
constexpr int BROWS = 4096;   // batch (M)
constexpr int DDIM  = 2048;   // input features (K)
constexpr int NCOMP = 4;
constexpr int DCOMP = 1024;
constexpr int NOUT  = NCOMP * DCOMP;  // 4096 output cols (N)

typedef __attribute__((ext_vector_type(8))) short bf16x8;
typedef __attribute__((ext_vector_type(4))) float f32x4;
typedef __attribute__((ext_vector_type(4))) short s16x4;

__device__ __forceinline__ short f2bf(float f) {
  union { float f; unsigned u; } v; v.f = f;
  unsigned r = v.u + 0x7FFFu + ((v.u >> 16) & 1u);  // round-to-nearest-even
  return (short)(r >> 16);
}

// global->LDS direct copy, 16B per lane. LDS dest = wave-uniform base + lane*16.
#define GLOAD_LDS16(gptr, lptr) __builtin_amdgcn_global_load_lds( \
    (const __attribute__((address_space(1))) void*)(gptr),        \
    (__attribute__((address_space(3))) void*)(lptr), 16, 0, 0)

// =======================================================================
// Prep kernel: blocks [0,1024) = gating + x f32->bf16; [1024,3072) = Wc
// transpose+convert to B^T bf16 layout. Block-uniform branch (safe syncs).
// =======================================================================
__global__ __launch_bounds__(256) void prep_kernel(
    const float* __restrict__ x, const float* __restrict__ noise,
    const float* __restrict__ Wg, const float* __restrict__ bg,
    const float* __restrict__ Wn, const float* __restrict__ bn,
    const float* __restrict__ Wc,
    float* __restrict__ Gout, short* __restrict__ xb, short* __restrict__ WcT) {
  __shared__ float tile[64][65];
  const int bid = blockIdx.x;
  const int tid = threadIdx.x;

  if (bid < 1024) {
    // ---- gating + convert: 4 rows per block, one wave per row ----
    const int lane = tid & 63;
    const int row  = bid * 4 + (tid >> 6);
    const float* xr = x + (size_t)row * DDIM;
    short* xbr = xb + (size_t)row * DDIM;

    float ag[4] = {0.f, 0.f, 0.f, 0.f};
    float an[4] = {0.f, 0.f, 0.f, 0.f};
#pragma unroll
    for (int i = 0; i < 8; i++) {
      int d = i * 256 + lane * 4;
      float4 v = *reinterpret_cast<const float4*>(xr + d);
      s16x4 s; s.x = f2bf(v.x); s.y = f2bf(v.y); s.z = f2bf(v.z); s.w = f2bf(v.w);
      *reinterpret_cast<s16x4*>(xbr + d) = s;
      float xv[4] = {v.x, v.y, v.z, v.w};
#pragma unroll
      for (int j = 0; j < 4; j++) {
        float4 wg = *reinterpret_cast<const float4*>(Wg + 4 * (d + j));
        float4 wn = *reinterpret_cast<const float4*>(Wn + 4 * (d + j));
        ag[0] += xv[j] * wg.x; ag[1] += xv[j] * wg.y;
        ag[2] += xv[j] * wg.z; ag[3] += xv[j] * wg.w;
        an[0] += xv[j] * wn.x; an[1] += xv[j] * wn.y;
        an[2] += xv[j] * wn.z; an[3] += xv[j] * wn.w;
      }
    }
#pragma unroll
    for (int off = 32; off > 0; off >>= 1) {
#pragma unroll
      for (int c = 0; c < 4; c++) {
        ag[c] += __shfl_xor(ag[c], off);
        an[c] += __shfl_xor(an[c], off);
      }
    }
    if (lane == 0) {
      float H[4];
#pragma unroll
      for (int c = 0; c < 4; c++) {
        float v  = an[c] + bn[c];
        float sp = (v > 20.f) ? v : log1pf(expf(v));   // stable softplus
        H[c] = (ag[c] + bg[c]) + noise[(size_t)row * NCOMP + c] * sp;
      }
      int k = 0; float best = H[0];
#pragma unroll
      for (int c = 1; c < 4; c++) { if (H[c] > best) { best = H[c]; k = c; } }
#pragma unroll
      for (int c = 0; c < 4; c++)
        Gout[(size_t)row * NCOMP + c] = (c <= k) ? 1.0f : 0.0f;
    }
  } else {
    // ---- transpose: Wc[c][d][o] f32 -> WcT[c*1024+o][d] bf16 ----
    const int tb  = bid - 1024;
    const int o_t = tb & 15, d_t = (tb >> 4) & 31, c = tb >> 9;
    const int d0 = d_t * 64, o0 = o_t * 64;
    const int col = tid & 63, rb = tid >> 6;

    const float* src = Wc + ((size_t)c * DDIM + d0) * DCOMP + o0;
#pragma unroll
    for (int i = 0; i < 16; i++) {
      int r = rb + i * 4;
      tile[r][col] = src[(size_t)r * DCOMP + col];   // tile[d][o]
    }
    __syncthreads();
    short* dst = WcT + ((size_t)c * DCOMP + o0) * DDIM + d0;
    const int o  = tid >> 2;            // 0..63
    const int dsb = (tid & 3) * 16;     // 0,16,32,48
    bf16x8 p0, p1;
#pragma unroll
    for (int k = 0; k < 8; k++) {
      p0[k] = f2bf(tile[dsb + k][o]);
      p1[k] = f2bf(tile[dsb + 8 + k][o]);
    }
    *reinterpret_cast<bf16x8*>(dst + (size_t)o * DDIM + dsb)     = p0;
    *reinterpret_cast<bf16x8*>(dst + (size_t)o * DDIM + dsb + 8) = p1;
  }
}

// =======================================================================
// Main GEMM: E = mask * (xb @ WcT^T + bc)
// 256x256 tile, BK=64, 8 waves (2Mx4N), 8-phase schedule, dbuf half-tile
// LDS (128 KiB), XOR-swizzled slots, counted vmcnt(4) at phases 4/8,
// setprio around MFMA clusters, XCD-aware block swizzle.
// Per-wave output 128x64: rows = wm*64+[0,64) in each A-half,
// cols = wn*32+[0,32) in each B-half -> staggered half read-windows.
// =======================================================================
constexpr int BM = 256, BN = 256, BK = 64;
constexpr int NT = DDIM / BK;    // 32 K-tiles
constexpr int HS = 128 * 64;     // shorts per half-tile (16 KB)

template<int MB, int NB>
__device__ __forceinline__ void MF(f32x4 (&acc)[8][4], bf16x8 (&a)[4][2], bf16x8 (&b)[2][2]) {
#pragma unroll
  for (int kh = 0; kh < 2; kh++)
#pragma unroll
    for (int ml = 0; ml < 4; ml++)
#pragma unroll
      for (int nl = 0; nl < 2; nl++)
        acc[MB + ml][NB + nl] = __builtin_amdgcn_mfma_f32_16x16x32_bf16(
            a[ml][kh], b[nl][kh], acc[MB + ml][NB + nl], 0, 0, 0);
}

// phase sync + MFMA cluster (template-mandated order; rule #18 sched_barrier)
#define PH_SYNC_MFMA(MB, NB)                                 \
  __builtin_amdgcn_s_barrier();                              \
  asm volatile("s_waitcnt lgkmcnt(0)" ::: "memory");         \
  __builtin_amdgcn_sched_barrier(0);                         \
  __builtin_amdgcn_s_setprio(1);                             \
  MF<MB, NB>(acc, a, b);                                     \
  __builtin_amdgcn_s_setprio(0);                             \
  __builtin_amdgcn_sched_barrier(0);

__global__ __launch_bounds__(512, 2) void gemm_kernel(
    const short* __restrict__ xb, const short* __restrict__ wt,
    const float* __restrict__ bc, const float* __restrict__ G,
    float* __restrict__ E) {
  __shared__ short Asm[2][2][HS];   // [buf][row-half][128r * 8slot * 8bf16]
  __shared__ short Bsm[2][2][HS];   // [buf][col-half][...]

  const int tid  = threadIdx.x;
  const int wave = tid >> 6, lane = tid & 63;
  const int wm = wave >> 2, wn = wave & 3;
  const int fr = lane & 15, fq = lane >> 4, l7 = lane & 7;

  // XCD swizzle (256 blocks, 8 XCDs, 256%8==0 -> bijective)
  const int swz = (blockIdx.x & 7) * 32 + (blockIdx.x >> 3);
  const int trow0 = (swz >> 4) * BM;
  const int tcol0 = (swz & 15) * BN;

  const short* baseA[2] = { xb + (size_t)(trow0      ) * DDIM,
                            xb + (size_t)(trow0 + 128) * DDIM };
  const short* baseB[2] = { wt + (size_t)(tcol0      ) * DDIM,
                            wt + (size_t)(tcol0 + 128) * DDIM };

  // per-lane pre-swizzled staging source offsets (rule #21: linear LDS dest,
  // inverse-swizzled global source, swizzled ds_read)
  size_t soff[2]; int ldst[2];
#pragma unroll
  for (int l = 0; l < 2; l++) {
    int f = l * 512 + tid;
    int r = f >> 3;
    int s = (f & 7) ^ (r & 7);
    soff[l] = (size_t)r * DDIM + s * 8;
    ldst[l] = (l * 512 + wave * 64) * 8;   // wave-uniform LDS base (shorts)
  }

  auto STAGE = [&](const short* gb, int t, short* ldsh) {
#pragma unroll
    for (int l = 0; l < 2; l++)
      GLOAD_LDS16(gb + t * 64 + soff[l], ldsh + ldst[l]);
  };
  auto LDA = [&](const short* Ah, bf16x8 (&a)[4][2]) {
#pragma unroll
    for (int ml = 0; ml < 4; ml++) {
      int rh = wm * 64 + ml * 16 + fr;
#pragma unroll
      for (int kh = 0; kh < 2; kh++) {
        int sl = ((kh * 4 + fq) ^ l7) * 8;
        a[ml][kh] = *reinterpret_cast<const bf16x8*>(Ah + rh * 64 + sl);
      }
    }
  };
  auto LDB = [&](const short* Bh, bf16x8 (&b)[2][2]) {
#pragma unroll
    for (int nl = 0; nl < 2; nl++) {
      int ch = wn * 32 + nl * 16 + fr;
#pragma unroll
      for (int kh = 0; kh < 2; kh++) {
        int sl = ((kh * 4 + fq) ^ l7) * 8;
        b[nl][kh] = *reinterpret_cast<const bf16x8*>(Bh + ch * 64 + sl);
      }
    }
  };

  f32x4 acc[8][4];
#pragma unroll
  for (int m = 0; m < 8; m++)
#pragma unroll
    for (int n = 0; n < 4; n++) acc[m][n] = f32x4{0.f, 0.f, 0.f, 0.f};
  bf16x8 a[4][2], b[2][2];

  // ---- prologue: tile0 -> buf0 (all 4 halves), tile1 -> buf1 {A-h0, B-h1} ----
  STAGE(baseA[0], 0, &Asm[0][0][0]);
  STAGE(baseA[1], 0, &Asm[0][1][0]);
  STAGE(baseB[0], 0, &Bsm[0][0][0]);
  STAGE(baseB[1], 0, &Bsm[0][1][0]);
  STAGE(baseA[0], 1, &Asm[1][0][0]);
  STAGE(baseB[1], 1, &Bsm[1][1][0]);
  asm volatile("s_waitcnt vmcnt(4)" ::: "memory");   // tile0 landed; tile1 pair in flight
  __builtin_amdgcn_s_barrier();

  // ---- main loop: iter i consumes tiles 2i (buf0, p1-4) and 2i+1 (buf1, p5-8).
  // Stage ledger (verified): p1:B1.Ah1<-t+1  p2:B1.Bh0<-t+1  p3:B0.Ah0<-t+2
  // p4:B0.Bh1<-t+2  p5:B0.Ah1<-t+2  p6:B0.Bh0<-t+2  p7:B1.Ah0<-t+3  p8:B1.Bh1<-t+3
  // vmcnt(4) at p4 covers tile t+1; at p8 covers tile t+2. Never 0 except last iter.
  for (int i = 0; i < NT / 2; i++) {
    const int t1 = 2 * i + 1, t2 = 2 * i + 2, t3 = 2 * i + 3;
    const bool more = (i < NT / 2 - 1);

    // p1: quadrant (mh0, nh0)
    LDA(&Asm[0][0][0], a); LDB(&Bsm[0][0][0], b);
    STAGE(baseA[1], t1, &Asm[1][1][0]);
    PH_SYNC_MFMA(0, 0);
    __builtin_amdgcn_s_barrier();
    // p2: (mh0, nh1)
    LDB(&Bsm[0][1][0], b);
    STAGE(baseB[0], t1, &Bsm[1][0][0]);
    PH_SYNC_MFMA(0, 2);
    __builtin_amdgcn_s_barrier();
    // p3: (mh1, nh1)
    LDA(&Asm[0][1][0], a);
    if (more) STAGE(baseA[0], t2, &Asm[0][0][0]);
    PH_SYNC_MFMA(4, 2);
    __builtin_amdgcn_s_barrier();
    // p4: (mh1, nh0)  + counted vmcnt
    LDB(&Bsm[0][0][0], b);
    if (more) STAGE(baseB[1], t2, &Bsm[0][1][0]);
    PH_SYNC_MFMA(4, 0);
    if (more) { asm volatile("s_waitcnt vmcnt(4)" ::: "memory"); }
    else      { asm volatile("s_waitcnt vmcnt(0)" ::: "memory"); }
    __builtin_amdgcn_s_barrier();
    // p5: (mh0, nh0) of buf1
    LDA(&Asm[1][0][0], a); LDB(&Bsm[1][0][0], b);
    if (more) STAGE(baseA[1], t2, &Asm[0][1][0]);
    PH_SYNC_MFMA(0, 0);
    __builtin_amdgcn_s_barrier();
    // p6: (mh0, nh1)
    LDB(&Bsm[1][1][0], b);
    if (more) STAGE(baseB[0], t2, &Bsm[0][0][0]);
    PH_SYNC_MFMA(0, 2);
    __builtin_amdgcn_s_barrier();
    // p7: (mh1, nh1)
    LDA(&Asm[1][1][0], a);
    if (more) STAGE(baseA[0], t3, &Asm[1][0][0]);
    PH_SYNC_MFMA(4, 2);
    __builtin_amdgcn_s_barrier();
    // p8: (mh1, nh0) + counted vmcnt
    LDB(&Bsm[1][0][0], b);
    if (more) STAGE(baseB[1], t3, &Bsm[1][1][0]);
    PH_SYNC_MFMA(4, 0);
    if (more) { asm volatile("s_waitcnt vmcnt(4)" ::: "memory"); }
    __builtin_amdgcn_s_barrier();
  }

  // ---- epilogue: + bias, * mask, store f32 ----
  const int comp = tcol0 >> 10;            // 256-col tile lies in one component
  const float* __restrict__ bcn = bc + (size_t)comp * DCOMP + (tcol0 & (DCOMP - 1));
  float bias[4];
#pragma unroll
  for (int n = 0; n < 4; n++)
    bias[n] = bcn[((n >> 1) * 128) + wn * 32 + (n & 1) * 16 + fr];
#pragma unroll
  for (int m = 0; m < 8; m++) {
    int growb = trow0 + ((m >> 2) * 128) + wm * 64 + (m & 3) * 16 + fq * 4;
#pragma unroll
    for (int j = 0; j < 4; j++) {
      int r = growb + j;
      float mval = G[(size_t)r * NCOMP + comp];
      float* Erow = E + (size_t)r * NOUT + tcol0;
#pragma unroll
      for (int n = 0; n < 4; n++) {
        int coll = ((n >> 1) * 128) + wn * 32 + (n & 1) * 16 + fr;
        Erow[coll] = mval * (acc[m][n][j] + bias[n]);
      }
    }
  }
}

extern "C" void kernel_launch(void* const* d_in, const int* in_sizes, int n_in,
                              void* d_out, int out_size, void* d_ws, size_t ws_size,
                              hipStream_t stream) {
  const float* x     = (const float*)d_in[0];
  const float* noise = (const float*)d_in[1];
  const float* Wc    = (const float*)d_in[2];
  const float* bc    = (const float*)d_in[3];
  const float* Wg    = (const float*)d_in[4];
  const float* bg    = (const float*)d_in[5];
  const float* Wn    = (const float*)d_in[6];
  const float* bn    = (const float*)d_in[7];

  float* E = (float*)d_out;                          // [4096, 4096]
  float* G = (float*)d_out + (size_t)BROWS * NOUT;   // [4096, 4]

  short* xb  = (short*)d_ws;                         // [4096][2048] bf16, 16 MB
  short* WcT = xb + (size_t)BROWS * DDIM;            // [4096][2048] bf16, 16 MB

  prep_kernel<<<3072, 256, 0, stream>>>(x, noise, Wg, bg, Wn, bn, Wc, G, xb, WcT);
  gemm_kernel<<<256, 512, 0, stream>>>(xb, WcT, bc, G, E);
}

// Round 5
// 95.617 us; speedup vs baseline: 1.7785x; 1.0213x over previous
//
#include <hip/hip_runtime.h>
#include <hip/hip_bf16.h>
#include <math.h>

// Problem constants (fixed by the reference)
constexpr int BROWS = 4096;   // batch (M)
constexpr int DDIM  = 2048;   // input features (K)
constexpr int NCOMP = 4;
constexpr int DCOMP = 1024;
constexpr int NOUT  = NCOMP * DCOMP;  // 4096 output cols (N)

typedef __attribute__((ext_vector_type(8))) short bf16x8;
typedef __attribute__((ext_vector_type(4))) float f32x4;
typedef __attribute__((ext_vector_type(4))) short s16x4;

__device__ __forceinline__ short f2bf(float f) {
  union { float f; unsigned u; } v; v.f = f;
  unsigned r = v.u + 0x7FFFu + ((v.u >> 16) & 1u);  // round-to-nearest-even
  return (short)(r >> 16);
}

// global->LDS direct copy, 16B per lane. LDS dest = wave-uniform base + lane*16.
#define GLOAD_LDS16(gptr, lptr) __builtin_amdgcn_global_load_lds( \
    (const __attribute__((address_space(1))) void*)(gptr),        \
    (__attribute__((address_space(3))) void*)(lptr), 16, 0, 0)

// =======================================================================
// Prep kernel: blocks [0,1024) = gating + x f32->bf16; [1024,3072) = Wc
// transpose+convert to B^T bf16 layout. Block-uniform branch (safe syncs).
// =======================================================================
__global__ __launch_bounds__(256) void prep_kernel(
    const float* __restrict__ x, const float* __restrict__ noise,
    const float* __restrict__ Wg, const float* __restrict__ bg,
    const float* __restrict__ Wn, const float* __restrict__ bn,
    const float* __restrict__ Wc,
    float* __restrict__ Gout, short* __restrict__ xb, short* __restrict__ WcT) {
  __shared__ float tile[64][65];
  const int bid = blockIdx.x;
  const int tid = threadIdx.x;

  if (bid < 1024) {
    // ---- gating + convert: 4 rows per block, one wave per row ----
    const int lane = tid & 63;
    const int row  = bid * 4 + (tid >> 6);
    const float* xr = x + (size_t)row * DDIM;
    short* xbr = xb + (size_t)row * DDIM;

    float ag[4] = {0.f, 0.f, 0.f, 0.f};
    float an[4] = {0.f, 0.f, 0.f, 0.f};
#pragma unroll
    for (int i = 0; i < 8; i++) {
      int d = i * 256 + lane * 4;
      float4 v = *reinterpret_cast<const float4*>(xr + d);
      s16x4 s; s.x = f2bf(v.x); s.y = f2bf(v.y); s.z = f2bf(v.z); s.w = f2bf(v.w);
      *reinterpret_cast<s16x4*>(xbr + d) = s;
      float xv[4] = {v.x, v.y, v.z, v.w};
#pragma unroll
      for (int j = 0; j < 4; j++) {
        float4 wg = *reinterpret_cast<const float4*>(Wg + 4 * (d + j));
        float4 wn = *reinterpret_cast<const float4*>(Wn + 4 * (d + j));
        ag[0] += xv[j] * wg.x; ag[1] += xv[j] * wg.y;
        ag[2] += xv[j] * wg.z; ag[3] += xv[j] * wg.w;
        an[0] += xv[j] * wn.x; an[1] += xv[j] * wn.y;
        an[2] += xv[j] * wn.z; an[3] += xv[j] * wn.w;
      }
    }
#pragma unroll
    for (int off = 32; off > 0; off >>= 1) {
#pragma unroll
      for (int c = 0; c < 4; c++) {
        ag[c] += __shfl_xor(ag[c], off);
        an[c] += __shfl_xor(an[c], off);
      }
    }
    if (lane == 0) {
      float H[4];
#pragma unroll
      for (int c = 0; c < 4; c++) {
        float v  = an[c] + bn[c];
        float sp = (v > 20.f) ? v : log1pf(expf(v));   // stable softplus
        H[c] = (ag[c] + bg[c]) + noise[(size_t)row * NCOMP + c] * sp;
      }
      int k = 0; float best = H[0];
#pragma unroll
      for (int c = 1; c < 4; c++) { if (H[c] > best) { best = H[c]; k = c; } }
#pragma unroll
      for (int c = 0; c < 4; c++)
        Gout[(size_t)row * NCOMP + c] = (c <= k) ? 1.0f : 0.0f;
    }
  } else {
    // ---- transpose: Wc[c][d][o] f32 -> WcT[c*1024+o][d] bf16 ----
    const int tb  = bid - 1024;
    const int o_t = tb & 15, d_t = (tb >> 4) & 31, c = tb >> 9;
    const int d0 = d_t * 64, o0 = o_t * 64;
    const int col = tid & 63, rb = tid >> 6;

    const float* src = Wc + ((size_t)c * DDIM + d0) * DCOMP + o0;
#pragma unroll
    for (int i = 0; i < 16; i++) {
      int r = rb + i * 4;
      tile[r][col] = src[(size_t)r * DCOMP + col];   // tile[d][o]
    }
    __syncthreads();
    short* dst = WcT + ((size_t)c * DCOMP + o0) * DDIM + d0;
    const int o  = tid >> 2;            // 0..63
    const int dsb = (tid & 3) * 16;     // 0,16,32,48
    bf16x8 p0, p1;
#pragma unroll
    for (int k = 0; k < 8; k++) {
      p0[k] = f2bf(tile[dsb + k][o]);
      p1[k] = f2bf(tile[dsb + 8 + k][o]);
    }
    *reinterpret_cast<bf16x8*>(dst + (size_t)o * DDIM + dsb)     = p0;
    *reinterpret_cast<bf16x8*>(dst + (size_t)o * DDIM + dsb + 8) = p1;
  }
}

// =======================================================================
// Main GEMM: E = mask * (xb @ WcT^T + bc)
// 256x256 tile, BK=64, 8 waves (2Mx4N), 8-phase m201-template schedule,
// dbuf half-tile LDS (128 KiB), XOR-swizzled slots, counted vmcnt(4) at
// phases 4/8 ("memory"-pinned), bare lgkmcnt(0) per phase, setprio around
// MFMA, XCD-aware 4x8 chunked block swizzle. Last iteration peeled —
// KEEPING its p1/p2 stages (buf1.Ah1/Bh0 <- tile NT-1), which round 4
// incorrectly dropped (stale tile-29 data -> absmax 1.45).
// =======================================================================
constexpr int BM = 256, BN = 256, BK = 64;
constexpr int NT = DDIM / BK;    // 32 K-tiles
constexpr int HS = 128 * 64;     // shorts per half-tile (16 KB)

template<int MB, int NB>
__device__ __forceinline__ void MF(f32x4 (&acc)[8][4], bf16x8 (&a)[4][2], bf16x8 (&b)[2][2]) {
#pragma unroll
  for (int kh = 0; kh < 2; kh++)
#pragma unroll
    for (int ml = 0; ml < 4; ml++)
#pragma unroll
      for (int nl = 0; nl < 2; nl++)
        acc[MB + ml][NB + nl] = __builtin_amdgcn_mfma_f32_16x16x32_bf16(
            a[ml][kh], b[nl][kh], acc[MB + ml][NB + nl], 0, 0, 0);
}

// m201-template phase sync: barrier -> bare lgkmcnt(0) -> prio MFMA cluster.
// No sched_barrier / no memory clobber: ds_read->MFMA deps are compiler-
// tracked; staging->ds_read ordering is pinned by the vmcnt(memory) asms.
#define PH_SYNC_MFMA(MB, NB)                                 \
  __builtin_amdgcn_s_barrier();                              \
  asm volatile("s_waitcnt lgkmcnt(0)");                      \
  __builtin_amdgcn_s_setprio(1);                             \
  MF<MB, NB>(acc, a, b);                                     \
  __builtin_amdgcn_s_setprio(0);

__global__ __launch_bounds__(512, 2) void gemm_kernel(
    const short* __restrict__ xb, const short* __restrict__ wt,
    const float* __restrict__ bc, const float* __restrict__ G,
    float* __restrict__ E) {
  __shared__ short Asm[2][2][HS];   // [buf][row-half][128r * 8slot * 8bf16]
  __shared__ short Bsm[2][2][HS];   // [buf][col-half][...]

  const int tid  = threadIdx.x;
  const int wave = tid >> 6, lane = tid & 63;
  const int wm = wave >> 2, wn = wave & 3;
  const int fr = lane & 15, fq = lane >> 4, l7 = lane & 7;

  // XCD swizzle: 16x16 tile grid, 8 XCDs, each owns a 4x8 chunk walked
  // column-major (A panels L2-resident, B panels read ~once per XCD).
  const int xcd = blockIdx.x & 7, j = blockIdx.x >> 3;
  const int trow0 = (((xcd >> 1) << 2) + (j & 3)) * BM;
  const int tcol0 = (((xcd & 1) << 3) + (j >> 2)) * BN;

  const short* baseA[2] = { xb + (size_t)(trow0      ) * DDIM,
                            xb + (size_t)(trow0 + 128) * DDIM };
  const short* baseB[2] = { wt + (size_t)(tcol0      ) * DDIM,
                            wt + (size_t)(tcol0 + 128) * DDIM };

  // per-lane pre-swizzled staging source offsets (rule #21: linear LDS dest,
  // inverse-swizzled global source, swizzled ds_read)
  size_t soff[2]; int ldst[2];
#pragma unroll
  for (int l = 0; l < 2; l++) {
    int f = l * 512 + tid;
    int r = f >> 3;
    int s = (f & 7) ^ (r & 7);
    soff[l] = (size_t)r * DDIM + s * 8;
    ldst[l] = (l * 512 + wave * 64) * 8;   // wave-uniform LDS base (shorts)
  }

  auto STAGE = [&](const short* gb, int t, short* ldsh) {
#pragma unroll
    for (int l = 0; l < 2; l++)
      GLOAD_LDS16(gb + t * 64 + soff[l], ldsh + ldst[l]);
  };
  auto LDA = [&](const short* Ah, bf16x8 (&a)[4][2]) {
#pragma unroll
    for (int ml = 0; ml < 4; ml++) {
      int rh = wm * 64 + ml * 16 + fr;
#pragma unroll
      for (int kh = 0; kh < 2; kh++) {
        int sl = ((kh * 4 + fq) ^ l7) * 8;
        a[ml][kh] = *reinterpret_cast<const bf16x8*>(Ah + rh * 64 + sl);
      }
    }
  };
  auto LDB = [&](const short* Bh, bf16x8 (&b)[2][2]) {
#pragma unroll
    for (int nl = 0; nl < 2; nl++) {
      int ch = wn * 32 + nl * 16 + fr;
#pragma unroll
      for (int kh = 0; kh < 2; kh++) {
        int sl = ((kh * 4 + fq) ^ l7) * 8;
        b[nl][kh] = *reinterpret_cast<const bf16x8*>(Bh + ch * 64 + sl);
      }
    }
  };

  f32x4 acc[8][4];
#pragma unroll
  for (int m = 0; m < 8; m++)
#pragma unroll
    for (int n = 0; n < 4; n++) acc[m][n] = f32x4{0.f, 0.f, 0.f, 0.f};
  bf16x8 a[4][2], b[2][2];

  // ---- prologue: tile0 -> buf0 (all 4 halves), tile1 -> buf1 {A-h0, B-h1} ----
  STAGE(baseA[0], 0, &Asm[0][0][0]);
  STAGE(baseA[1], 0, &Asm[0][1][0]);
  STAGE(baseB[0], 0, &Bsm[0][0][0]);
  STAGE(baseB[1], 0, &Bsm[0][1][0]);
  STAGE(baseA[0], 1, &Asm[1][0][0]);
  STAGE(baseB[1], 1, &Bsm[1][1][0]);
  asm volatile("s_waitcnt vmcnt(4)" ::: "memory");   // tile0 landed; tile1 pair in flight
  __builtin_amdgcn_s_barrier();

  // ---- main loop (iters 0..NT/2-2, branch-free): iter i consumes tiles 2i
  // (buf0, p1-4) and 2i+1 (buf1, p5-8). Stage ledger (audited r4):
  // p1:B1.Ah1<-t1  p2:B1.Bh0<-t1  p3:B0.Ah0<-t2  p4:B0.Bh1<-t2
  // p5:B0.Ah1<-t2  p6:B0.Bh0<-t2  p7:B1.Ah0<-t3  p8:B1.Bh1<-t3
  // vmcnt(4) at p4 lands {prev p7,p8, this p1,p2} stages (incl. same-iter
  // buf1.Ah1/Bh0 read at p5-p8); vmcnt(4) at p8 lands {p3..p6} = buf0 of
  // next iter. Never 0 in steady state.
  for (int i = 0; i < NT / 2 - 1; i++) {
    const int t1 = 2 * i + 1, t2 = 2 * i + 2, t3 = 2 * i + 3;

    // p1: quadrant (mh0, nh0) of buf0
    LDA(&Asm[0][0][0], a); LDB(&Bsm[0][0][0], b);
    STAGE(baseA[1], t1, &Asm[1][1][0]);
    PH_SYNC_MFMA(0, 0);
    __builtin_amdgcn_s_barrier();
    // p2: (mh0, nh1)
    LDB(&Bsm[0][1][0], b);
    STAGE(baseB[0], t1, &Bsm[1][0][0]);
    PH_SYNC_MFMA(0, 2);
    __builtin_amdgcn_s_barrier();
    // p3: (mh1, nh1)
    LDA(&Asm[0][1][0], a);
    STAGE(baseA[0], t2, &Asm[0][0][0]);
    PH_SYNC_MFMA(4, 2);
    __builtin_amdgcn_s_barrier();
    // p4: (mh1, nh0) + counted vmcnt
    LDB(&Bsm[0][0][0], b);
    STAGE(baseB[1], t2, &Bsm[0][1][0]);
    PH_SYNC_MFMA(4, 0);
    asm volatile("s_waitcnt vmcnt(4)" ::: "memory");
    __builtin_amdgcn_s_barrier();
    // p5: (mh0, nh0) of buf1
    LDA(&Asm[1][0][0], a); LDB(&Bsm[1][0][0], b);
    STAGE(baseA[1], t2, &Asm[0][1][0]);
    PH_SYNC_MFMA(0, 0);
    __builtin_amdgcn_s_barrier();
    // p6: (mh0, nh1)
    LDB(&Bsm[1][1][0], b);
    STAGE(baseB[0], t2, &Bsm[0][0][0]);
    PH_SYNC_MFMA(0, 2);
    __builtin_amdgcn_s_barrier();
    // p7: (mh1, nh1)
    LDA(&Asm[1][1][0], a);
    STAGE(baseA[0], t3, &Asm[1][0][0]);
    PH_SYNC_MFMA(4, 2);
    __builtin_amdgcn_s_barrier();
    // p8: (mh1, nh0) + counted vmcnt
    LDB(&Bsm[1][0][0], b);
    STAGE(baseB[1], t3, &Bsm[1][1][0]);
    PH_SYNC_MFMA(4, 0);
    asm volatile("s_waitcnt vmcnt(4)" ::: "memory");
    __builtin_amdgcn_s_barrier();
  }

  // ---- peeled last iteration (tiles NT-2 in buf0, NT-1 in buf1) ----
  // MUST keep the p1/p2 stages: buf1.Ah1 and buf1.Bh0 for tile NT-1 are
  // staged by the consuming iteration itself (see ledger). Only the t2/t3
  // stages (next iter's tiles) are dropped.
  {
    // p1 (+ stage buf1.Ah1 <- tile NT-1)
    LDA(&Asm[0][0][0], a); LDB(&Bsm[0][0][0], b);
    STAGE(baseA[1], NT - 1, &Asm[1][1][0]);
    PH_SYNC_MFMA(0, 0);
    __builtin_amdgcn_s_barrier();
    // p2 (+ stage buf1.Bh0 <- tile NT-1)
    LDB(&Bsm[0][1][0], b);
    STAGE(baseB[0], NT - 1, &Bsm[1][0][0]);
    PH_SYNC_MFMA(0, 2);
    __builtin_amdgcn_s_barrier();
    // p3
    LDA(&Asm[0][1][0], a);
    PH_SYNC_MFMA(4, 2);
    __builtin_amdgcn_s_barrier();
    // p4 + full drain (prev-iter p7/p8 stages and peel p1/p2 stages land)
    LDB(&Bsm[0][0][0], b);
    PH_SYNC_MFMA(4, 0);
    asm volatile("s_waitcnt vmcnt(0)" ::: "memory");
    __builtin_amdgcn_s_barrier();
    // p5
    LDA(&Asm[1][0][0], a); LDB(&Bsm[1][0][0], b);
    PH_SYNC_MFMA(0, 0);
    __builtin_amdgcn_s_barrier();
    // p6
    LDB(&Bsm[1][1][0], b);
    PH_SYNC_MFMA(0, 2);
    __builtin_amdgcn_s_barrier();
    // p7
    LDA(&Asm[1][1][0], a);
    PH_SYNC_MFMA(4, 2);
    __builtin_amdgcn_s_barrier();
    // p8
    LDB(&Bsm[1][0][0], b);
    PH_SYNC_MFMA(4, 0);
  }

  // ---- epilogue: + bias, * mask, store f32 ----
  const int comp = tcol0 >> 10;            // 256-col tile lies in one component
  const float* __restrict__ bcn = bc + (size_t)comp * DCOMP + (tcol0 & (DCOMP - 1));
  float bias[4];
#pragma unroll
  for (int n = 0; n < 4; n++)
    bias[n] = bcn[((n >> 1) * 128) + wn * 32 + (n & 1) * 16 + fr];
#pragma unroll
  for (int m = 0; m < 8; m++) {
    int growb = trow0 + ((m >> 2) * 128) + wm * 64 + (m & 3) * 16 + fq * 4;
#pragma unroll
    for (int j = 0; j < 4; j++) {
      int r = growb + j;
      float mval = G[(size_t)r * NCOMP + comp];
      float* Erow = E + (size_t)r * NOUT + tcol0;
#pragma unroll
      for (int n = 0; n < 4; n++) {
        int coll = ((n >> 1) * 128) + wn * 32 + (n & 1) * 16 + fr;
        Erow[coll] = mval * (acc[m][n][j] + bias[n]);
      }
    }
  }
}

extern "C" void kernel_launch(void* const* d_in, const int* in_sizes, int n_in,
                              void* d_out, int out_size, void* d_ws, size_t ws_size,
                              hipStream_t stream) {
  const float* x     = (const float*)d_in[0];
  const float* noise = (const float*)d_in[1];
  const float* Wc    = (const float*)d_in[2];
  const float* bc    = (const float*)d_in[3];
  const float* Wg    = (const float*)d_in[4];
  const float* bg    = (const float*)d_in[5];
  const float* Wn    = (const float*)d_in[6];
  const float* bn    = (const float*)d_in[7];

  float* E = (float*)d_out;                          // [4096, 4096]
  float* G = (float*)d_out + (size_t)BROWS * NOUT;   // [4096, 4]

  short* xb  = (short*)d_ws;                         // [4096][2048] bf16, 16 MB
  short* WcT = xb + (size_t)BROWS * DDIM;            // [4096][2048] bf16, 16 MB

  prep_kernel<<<3072, 256, 0, stream>>>(x, noise, Wg, bg, Wn, bn, Wc, G, xb, WcT);
  gemm_kernel<<<256, 512, 0, stream>>>(xb, WcT, bc, G, E);
}